// Round 12
// baseline (89.009 us; speedup 1.0000x reference)
//
#include <hip/hip_runtime.h>
#include <hip/hip_bf16.h>
#include <math.h>

#define BB    256   // batch
#define LL    256   // seq len
#define NV    14    // vocab
#define EMBD  512
#define H2    128   // L//2
#define OC    256   // branch conv out channels
#define NP    196   // 14*14 ordered token pairs
#define JD    128   // branch linear out
#define MO    64    // manip conv out channels
#define MJ    256   // manip linear out

// prep block ranges
#define PB_CWT    256                   // 2 br * 4 o-chunks * 32 i-chunks
#define PB_MANIPW 96
#define PB_LINT   64

using s16x8 = __attribute__((ext_vector_type(8))) short;
using f32x4 = __attribute__((ext_vector_type(4))) float;

static __device__ __forceinline__ unsigned short f2bf_rne(float f) {
    unsigned int u = __float_as_uint(f);
    unsigned int r = (u + 0x7FFFu + ((u >> 16) & 1u)) >> 16;
    return (unsigned short)r;
}
static __device__ __forceinline__ float bf2f(unsigned short h) {
    return __uint_as_float(((unsigned int)h) << 16);
}

// ---------- combined prep: cwt (LDS transpose) | manipw | lint ----------
__global__ void k_prep(const float* __restrict__ cw_e, const float* __restrict__ cw_f,
                       const float* __restrict__ mcw, const float* __restrict__ mlw,
                       float* __restrict__ cwT, float* __restrict__ Wc,
                       float* __restrict__ Lint) {
    __shared__ float T[48][66];   // cwt transpose tile
    int bid = blockIdx.x;
    int t = threadIdx.x;
    if (bid < PB_CWT) {                    // cwt: coalesced read + LDS transpose
        int cb = bid;                      // 0..255
        int ic = cb & 31;                  // i-chunk (16 i's)
        int oc = (cb >> 5) & 3;            // o-chunk (64 o's)
        int br = cb >> 7;                  // branch
        int i0 = ic * 16, o0 = oc * 64;
        const float* cw = br ? cw_f : cw_e;
        int ol = t >> 2, part = t & 3;     // o_local 0..63, i-quarter 0..3
        const float* src = cw + ((size_t)(o0 + ol) * EMBD + i0) * 9 + part * 36;
        #pragma unroll
        for (int ii = 0; ii < 4; ++ii)
            #pragma unroll
            for (int kh = 0; kh < 3; ++kh)
                T[kh * 16 + part * 4 + ii][ol] = src[ii * 9 + kh * 3 + 1];
        __syncthreads();
        int lane = t & 63, r0 = t >> 6;
        for (int rr = r0; rr < 48; rr += 4) {
            int kh = rr >> 4, il = rr & 15;
            cwT[(((size_t)(br * 3 + kh)) * EMBD + i0 + il) * OC + o0 + lane] = T[rr][lane];
        }
    } else if (bid < PB_CWT + PB_MANIPW) { // manipw
        int idx = (bid - PB_CWT) * 256 + t;
        int o = idx & 63;
        int i = (idx >> 6) & 127;
        int cls = idx >> 13;
        const float* base = mcw + ((size_t)(o * 128 + i) * 3) * 3 + 1;
        float v = 0.f;
        if (cls != 2) { v += base[3]; v += base[6]; }
        else          { v += base[0]; v += base[3]; }
        if (cls == 1)   v += base[0];
        Wc[idx] = v;
    } else {                                // lint (full interior sum)
        int o = bid - (PB_CWT + PB_MANIPW);   // 0..63
        float s = 0.f;
        for (int h = 1; h <= 126; h++)
            s += mlw[((size_t)(o * H2 + h)) * MJ + t];
        Lint[o * 256 + t] = s;
    }
}

// ---------- pair contributions, i-split x2, q-batch 4, inline pair-max ----------
__global__ __launch_bounds__(512) void k_contrib(
        const float* __restrict__ emb_e, const float* __restrict__ emb_f,
        const float* __restrict__ cwT,
        const float* __restrict__ cb_e, const float* __restrict__ cb_f,
        float* __restrict__ C) {
    int bid = blockIdx.x;               // (br*3+kh)*49+qg
    int qg = bid % 49;
    int kh = (bid / 49) % 3;
    int br = bid / 147;
    int t = threadIdx.x;
    int o = t & 255, ih = t >> 8;       // o output, i-half 0/1
    const float* emb = br ? emb_f : emb_e;

    __shared__ float Pl[4][512];
    __shared__ float Rd[4][2][256];
    for (int idx = t; idx < 4 * 512; idx += 512) {
        int row = idx >> 9, col = idx & 511;
        int q = qg * 4 + row;
        int t1 = q / NV, t2 = q % NV;
        Pl[row][col] = fmaxf(emb[t1 * EMBD + col], emb[t2 * EMBD + col]);
    }
    __syncthreads();

    const float* w = cwT + ((size_t)(br * 3 + kh) * EMBD + ih * 256) * OC + o;
    float acc[4] = {0.f, 0.f, 0.f, 0.f};
    #pragma unroll 8
    for (int i = 0; i < 256; i++) {
        float wv = w[(size_t)i * OC];
        #pragma unroll
        for (int qq = 0; qq < 4; qq++) acc[qq] = fmaf(wv, Pl[qq][ih * 256 + i], acc[qq]);
    }
    #pragma unroll
    for (int qq = 0; qq < 4; qq++) Rd[qq][ih][o] = acc[qq];
    __syncthreads();
    if (t < 256) {
        float cbv = (kh == 1) ? (br ? cb_f[o] : cb_e[o]) : 0.f;
        #pragma unroll
        for (int qq = 0; qq < 4; qq++)
            C[(((size_t)br * NP + qg * 4 + qq) * 3 + kh) * OC + o] =
                Rd[qq][0][o] + Rd[qq][1][o] + cbv;
    }
}

// ---------- enemy MFMA GEMM (X3 bf16 hi/lo split), double-buffered SK=32 ----------
template <int X3, int SK>
__global__ __launch_bounds__(512) void k_gemm(
        const int* __restrict__ tok, const float* __restrict__ C,
        const float* __restrict__ lw, float* __restrict__ partial) {
    __shared__ unsigned short Ah[2][64][SK + 4];
    __shared__ unsigned short Al[X3 ? 2 : 1][X3 ? 64 : 1][X3 ? SK + 4 : 1];
    __shared__ unsigned short Bh[2][128][SK + 4];
    __shared__ unsigned short Bl[X3 ? 2 : 1][X3 ? 128 : 1][X3 ? SK + 4 : 1];

    const int h  = blockIdx.x;
    const int B0 = blockIdx.y * 64;
    const int t  = threadIdx.x;
    constexpr int NST = 256 / SK;       // stages
    constexpr int KQ  = SK / 8;         // A floats per thread (per C-row)
    constexpr int KPT = SK / 16;        // B k's per thread

    // ---- A gather setup (thread: row am 0..63, k-chunk kq of KQ floats)
    const int am = t >> 3;
    const int kq = (t & 7) * KQ;
    const int* tb = tok + (size_t)(B0 + am) * LL;
    const int q1 = tb[2 * h] * NV + tb[2 * h + 1];
    const float* r1 = C + ((size_t)q1 * 3 + 1) * OC + kq;
    const float* r0 = nullptr;
    const float* r2 = nullptr;
    if (h > 0)      { int q0 = tb[2 * h - 2] * NV + tb[2 * h - 1]; r0 = C + ((size_t)q0 * 3 + 0) * OC + kq; }
    if (h < H2 - 1) { int q2 = tb[2 * h + 2] * NV + tb[2 * h + 3]; r2 = C + ((size_t)q2 * 3 + 2) * OC + kq; }

    // ---- B setup (thread: 4 j's at j0b, KPT k's at k0)
    const int j0b = (t & 31) * 4;
    const int k0  = (t >> 5) * KPT;
    const float* wsrc = lw + (((size_t)k0 * H2) + h) * JD + j0b;

    float4 ya[SK / 32], yb[SK / 32], yc[SK / 32], wv4[KPT];

    auto load = [&](int s) {
        #pragma unroll
        for (int p = 0; p < SK / 32; ++p) {
            ya[p] = *(const float4*)(r1 + s * SK + 4 * p);
            if (r0) yb[p] = *(const float4*)(r0 + s * SK + 4 * p);
            else    yb[p] = make_float4(0, 0, 0, 0);
            if (r2) yc[p] = *(const float4*)(r2 + s * SK + 4 * p);
            else    yc[p] = make_float4(0, 0, 0, 0);
        }
        #pragma unroll
        for (int kk = 0; kk < KPT; ++kk)
            wv4[kk] = *(const float4*)(wsrc + ((size_t)(s * SK) + kk) * (H2 * JD));
    };

    auto store = [&](int buf) {
        #pragma unroll
        for (int p = 0; p < SK / 32; ++p) {
            float y[4];
            y[0] = ya[p].x + yb[p].x + yc[p].x; y[1] = ya[p].y + yb[p].y + yc[p].y;
            y[2] = ya[p].z + yb[p].z + yc[p].z; y[3] = ya[p].w + yb[p].w + yc[p].w;
            unsigned short hi[4];
            #pragma unroll
            for (int e = 0; e < 4; ++e) hi[e] = f2bf_rne(y[e]);
            uint2 u;
            u.x = (unsigned)hi[0] | ((unsigned)hi[1] << 16);
            u.y = (unsigned)hi[2] | ((unsigned)hi[3] << 16);
            *(uint2*)&Ah[buf][am][kq + 4 * p] = u;
            if (X3) {
                unsigned short lo[4];
                #pragma unroll
                for (int e = 0; e < 4; ++e) lo[e] = f2bf_rne(y[e] - bf2f(hi[e]));
                uint2 v;
                v.x = (unsigned)lo[0] | ((unsigned)lo[1] << 16);
                v.y = (unsigned)lo[2] | ((unsigned)lo[3] << 16);
                *(uint2*)&Al[buf][am][kq + 4 * p] = v;
            }
        }
        // B: in-register 4j x KPT-k transpose; one packed LDS write per j
        #pragma unroll
        for (int jj = 0; jj < 4; ++jj) {
            unsigned short hb[KPT], lb[KPT];
            #pragma unroll
            for (int kk = 0; kk < KPT; ++kk) {
                float wf = ((const float*)&wv4[kk])[jj];
                hb[kk] = f2bf_rne(wf);
                if (X3) lb[kk] = f2bf_rne(wf - bf2f(hb[kk]));
            }
            if constexpr (KPT == 2) {
                *(unsigned*)&Bh[buf][j0b + jj][k0] = (unsigned)hb[0] | ((unsigned)hb[1] << 16);
                if (X3) *(unsigned*)&Bl[buf][j0b + jj][k0] = (unsigned)lb[0] | ((unsigned)lb[1] << 16);
            } else {
                uint2 u;
                u.x = (unsigned)hb[0] | ((unsigned)hb[1] << 16);
                u.y = (unsigned)hb[2] | ((unsigned)hb[3] << 16);
                *(uint2*)&Bh[buf][j0b + jj][k0] = u;
                if (X3) {
                    uint2 v;
                    v.x = (unsigned)lb[0] | ((unsigned)lb[1] << 16);
                    v.y = (unsigned)lb[2] | ((unsigned)lb[3] << 16);
                    *(uint2*)&Bl[buf][j0b + jj][k0] = v;
                }
            }
        }
    };

    // ---- compute mapping: 8 waves = 2m x 4n; wave tile 32m x 32n
    const int lane = t & 63, wid = t >> 6;
    const int Wm = (wid >> 2) * 32;     // 0 or 32
    const int Wn = (wid & 3) * 32;      // 0,32,64,96
    const int fr = lane & 15;
    const int g8 = (lane >> 4) * 8;

    f32x4 acc[2][2] = {};

    auto rd8 = [&](const unsigned short* p) -> s16x8 {
        union { s16x8 v; uint2 u[2]; } tmp;
        tmp.u[0] = *(const uint2*)(p);
        tmp.u[1] = *(const uint2*)(p + 4);
        return tmp.v;
    };

    auto compute = [&](int buf) {
        #pragma unroll
        for (int kk0 = 0; kk0 < SK; kk0 += 32) {
            s16x8 a_h[2], b_h[2];
            #pragma unroll
            for (int mf = 0; mf < 2; ++mf) a_h[mf] = rd8(&Ah[buf][Wm + mf * 16 + fr][kk0 + g8]);
            #pragma unroll
            for (int nf = 0; nf < 2; ++nf) b_h[nf] = rd8(&Bh[buf][Wn + nf * 16 + fr][kk0 + g8]);
            #pragma unroll
            for (int mf = 0; mf < 2; ++mf)
                #pragma unroll
                for (int nf = 0; nf < 2; ++nf)
                    acc[mf][nf] = __builtin_amdgcn_mfma_f32_16x16x32_bf16(a_h[mf], b_h[nf], acc[mf][nf], 0, 0, 0);
            if (X3) {
                s16x8 a_l[2], b_l[2];
                #pragma unroll
                for (int mf = 0; mf < 2; ++mf) a_l[mf] = rd8(&Al[buf][Wm + mf * 16 + fr][kk0 + g8]);
                #pragma unroll
                for (int nf = 0; nf < 2; ++nf) b_l[nf] = rd8(&Bl[buf][Wn + nf * 16 + fr][kk0 + g8]);
                #pragma unroll
                for (int mf = 0; mf < 2; ++mf)
                    #pragma unroll
                    for (int nf = 0; nf < 2; ++nf) {
                        acc[mf][nf] = __builtin_amdgcn_mfma_f32_16x16x32_bf16(a_h[mf], b_l[nf], acc[mf][nf], 0, 0, 0);
                        acc[mf][nf] = __builtin_amdgcn_mfma_f32_16x16x32_bf16(a_l[mf], b_h[nf], acc[mf][nf], 0, 0, 0);
                    }
            }
        }
    };

    // ---- main loop
    load(0);
    store(0);
    __syncthreads();
    for (int s = 0; s < NST; ++s) {
        if (s < NST - 1) load(s + 1);
        compute(s & 1);
        if (s < NST - 1) store((s + 1) & 1);
        __syncthreads();
    }

    // ---- epilogue: partial[b][h][j]; D mapping col=lane&15, row=4*(lane>>4)+reg
    float* pb = partial + (((size_t)(B0 + Wm)) * H2 + h) * JD + Wn;
    #pragma unroll
    for (int mf = 0; mf < 2; ++mf)
        #pragma unroll
        for (int nf = 0; nf < 2; ++nf)
            #pragma unroll
            for (int r = 0; r < 4; ++r) {
                int row = mf * 16 + (lane >> 4) * 4 + r;
                int col = nf * 16 + fr;
                pb[(size_t)row * H2 * JD + col] = acc[mf][nf][r];
            }
}

// ---------- friend MFMA GEMM: single-barrier, full-K LDS, M-tile 128 ----------
// LDS: A 128x256 bf16 + B 128x256 bf16 (pitch 264) = 135 KB, 1 block/CU.
// All global loads issue before ONE barrier (fully pipelined, no per-stage
// drains), then 64 back-to-back MFMA per wave. K ascending -> bitwise
// identical to the staged version.
__global__ __launch_bounds__(512) void k_gemmF1(
        const int* __restrict__ tok, const float* __restrict__ C,
        const float* __restrict__ lw, float* __restrict__ partial) {
    __shared__ unsigned short Ab[128][264];
    __shared__ unsigned short Bb[128][264];

    const int h  = blockIdx.x;
    const int B0 = blockIdx.y * 128;
    const int t  = threadIdx.x;

    // ---- A: row am 0..127 (4 threads/row), k-quarter kq
    const int am = t >> 2;
    const int kq = (t & 3) * 64;
    const int* tb = tok + (size_t)(B0 + am) * LL;
    const int q1 = tb[2 * h] * NV + tb[2 * h + 1];
    const float* r1 = C + ((size_t)q1 * 3 + 1) * OC + kq;
    const float* r0 = nullptr;
    const float* r2 = nullptr;
    if (h > 0)      { int q0 = tb[2 * h - 2] * NV + tb[2 * h - 1]; r0 = C + ((size_t)q0 * 3 + 0) * OC + kq; }
    if (h < H2 - 1) { int q2 = tb[2 * h + 2] * NV + tb[2 * h + 3]; r2 = C + ((size_t)q2 * 3 + 2) * OC + kq; }

    #pragma unroll
    for (int p = 0; p < 16; ++p) {
        float4 a = *(const float4*)(r1 + 4 * p);
        float4 b = r0 ? *(const float4*)(r0 + 4 * p) : make_float4(0, 0, 0, 0);
        float4 c = r2 ? *(const float4*)(r2 + 4 * p) : make_float4(0, 0, 0, 0);
        unsigned short h0 = f2bf_rne(a.x + b.x + c.x);
        unsigned short h1 = f2bf_rne(a.y + b.y + c.y);
        unsigned short h2 = f2bf_rne(a.z + b.z + c.z);
        unsigned short h3 = f2bf_rne(a.w + b.w + c.w);
        uint2 u;
        u.x = (unsigned)h0 | ((unsigned)h1 << 16);
        u.y = (unsigned)h2 | ((unsigned)h3 << 16);
        *(uint2*)&Ab[am][kq + 4 * p] = u;
    }

    // ---- B: 4 j's at j0b, 16 k's at k0; two 8-k chunks to bound registers
    const int j0b = (t & 31) * 4;
    const int k0  = (t >> 5) * 16;
    const float* wsrc = lw + ((size_t)k0 * H2 + h) * JD + j0b;
    #pragma unroll
    for (int cchunk = 0; cchunk < 2; ++cchunk) {
        unsigned short hb[4][8];
        #pragma unroll
        for (int kk = 0; kk < 8; ++kk) {
            float4 v = *(const float4*)(wsrc + ((size_t)(cchunk * 8 + kk)) * (H2 * JD));
            hb[0][kk] = f2bf_rne(v.x);
            hb[1][kk] = f2bf_rne(v.y);
            hb[2][kk] = f2bf_rne(v.z);
            hb[3][kk] = f2bf_rne(v.w);
        }
        #pragma unroll
        for (int jj = 0; jj < 4; ++jj) {
            uint2 u0, u1;
            u0.x = (unsigned)hb[jj][0] | ((unsigned)hb[jj][1] << 16);
            u0.y = (unsigned)hb[jj][2] | ((unsigned)hb[jj][3] << 16);
            u1.x = (unsigned)hb[jj][4] | ((unsigned)hb[jj][5] << 16);
            u1.y = (unsigned)hb[jj][6] | ((unsigned)hb[jj][7] << 16);
            *(uint2*)&Bb[j0b + jj][k0 + cchunk * 8]     = u0;
            *(uint2*)&Bb[j0b + jj][k0 + cchunk * 8 + 4] = u1;
        }
    }
    __syncthreads();

    // ---- compute: 8 waves 2m x 4n; wave tile 64m x 32n
    const int lane = t & 63, wid = t >> 6;
    const int Wm = (wid >> 2) * 64;     // 0 or 64
    const int Wn = (wid & 3) * 32;      // 0,32,64,96
    const int fr = lane & 15;
    const int g8 = (lane >> 4) * 8;

    f32x4 acc[4][2] = {};

    auto rd8 = [&](const unsigned short* p) -> s16x8 {
        union { s16x8 v; uint2 u[2]; } tmp;
        tmp.u[0] = *(const uint2*)(p);
        tmp.u[1] = *(const uint2*)(p + 4);
        return tmp.v;
    };

    for (int ks = 0; ks < 8; ++ks) {    // k-chunk of 32, ascending
        s16x8 a_h[4], b_h[2];
        #pragma unroll
        for (int mf = 0; mf < 4; ++mf) a_h[mf] = rd8(&Ab[Wm + mf * 16 + fr][ks * 32 + g8]);
        #pragma unroll
        for (int nf = 0; nf < 2; ++nf) b_h[nf] = rd8(&Bb[Wn + nf * 16 + fr][ks * 32 + g8]);
        #pragma unroll
        for (int mf = 0; mf < 4; ++mf)
            #pragma unroll
            for (int nf = 0; nf < 2; ++nf)
                acc[mf][nf] = __builtin_amdgcn_mfma_f32_16x16x32_bf16(a_h[mf], b_h[nf], acc[mf][nf], 0, 0, 0);
    }

    // ---- epilogue: partial[b][h][j]
    float* pb = partial + (((size_t)(B0 + Wm)) * H2 + h) * JD + Wn;
    #pragma unroll
    for (int mf = 0; mf < 4; ++mf)
        #pragma unroll
        for (int nf = 0; nf < 2; ++nf)
            #pragma unroll
            for (int r = 0; r < 4; ++r) {
                int row = mf * 16 + (lane >> 4) * 4 + r;
                int col = nf * 16 + fr;
                pb[(size_t)row * H2 * JD + col] = acc[mf][nf][r];
            }
}

// ---------- fuse E: reduce + softmax + manip conv + manip linear + tokens ----------
__global__ __launch_bounds__(256) void k_fuseE(
        const float* __restrict__ partial, const float* __restrict__ elb,
        const float* __restrict__ Wc, const float* __restrict__ mcb,
        const float* __restrict__ mlw, const float* __restrict__ Lint,
        const float* __restrict__ mlb, int* __restrict__ tokens) {
    int b = blockIdx.x, t = threadIdx.x;
    __shared__ float S[2][128];
    __shared__ float eo[128];
    __shared__ float m3[3][64];
    __shared__ float red[128];

    int j = t & 127, hh = t >> 7;
    float s = 0.f;
    const float* pbase = partial + (size_t)b * H2 * JD + j;
    for (int h = hh * 64; h < hh * 64 + 64; ++h)
        s += pbase[(size_t)h * JD];
    S[hh][j] = s;
    __syncthreads();
    if (t < 128) {
        float v = S[0][t] + S[1][t] + elb[t];
        S[0][t] = v;
        red[t] = v;
    }
    __syncthreads();
    for (int st = 64; st > 0; st >>= 1) {
        if (t < st) red[t] = fmaxf(red[t], red[t + st]);
        __syncthreads();
    }
    float mx = red[0];
    __syncthreads();
    if (t < 128) {
        float e = expf(S[0][t] - mx);
        eo[t] = e;
        red[t] = e;
    }
    __syncthreads();
    for (int st = 64; st > 0; st >>= 1) {
        if (t < st) red[t] += red[t + st];
        __syncthreads();
    }
    float inv = 1.f / red[0];
    __syncthreads();
    if (t < 128) eo[t] *= inv;
    __syncthreads();
    // manip conv values
    if (t < 192) {
        int cls = t >> 6, o = t & 63;
        float a = mcb[o];
        const float* wp = Wc + (size_t)cls * 128 * 64 + o;
        for (int i = 0; i < 128; ++i) a = fmaf(eo[i], wp[(size_t)i * 64], a);
        m3[cls][o] = fmaxf(a, 0.f);
    }
    __syncthreads();
    // manip linear + token quantization (t = j 0..255)
    float a = mlb[t];
    for (int o = 0; o < MO; ++o) {
        a = fmaf(m3[0][o], mlw[((size_t)(o * H2 + 0)) * MJ + t], a);
        a = fmaf(m3[1][o], Lint[(size_t)o * MJ + t], a);
        a = fmaf(m3[2][o], mlw[((size_t)(o * H2 + 127)) * MJ + t], a);
    }
    tokens[(size_t)b * LL + t] = ((int)floorf(fabsf(a) * 100.f)) % NV;
}

// ---------- fuse F: reduce + head linear + softmax(14) ----------
__global__ __launch_bounds__(256) void k_fuseF(
        const float* __restrict__ partial, const float* __restrict__ flb1,
        const float* __restrict__ fl2, const float* __restrict__ fb2,
        float* __restrict__ outp) {
    int b = blockIdx.x, t = threadIdx.x;
    __shared__ float S[2][128];
    __shared__ float f1[128];
    __shared__ float sl[NV];
    int j = t & 127, hh = t >> 7;
    float s = 0.f;
    const float* pbase = partial + (size_t)b * H2 * JD + j;
    for (int h = hh * 64; h < hh * 64 + 64; ++h)
        s += pbase[(size_t)h * JD];
    S[hh][j] = s;
    __syncthreads();
    if (t < 128) f1[t] = S[0][t] + S[1][t] + flb1[t];
    __syncthreads();
    if (t < NV) {
        float a = fb2[t];
        for (int jj = 0; jj < 128; ++jj) a = fmaf(f1[jj], fl2[(size_t)jj * NV + t], a);
        sl[t] = a;
    }
    __syncthreads();
    if (t < NV) {
        float mx = -1e30f;
        for (int u = 0; u < NV; ++u) mx = fmaxf(mx, sl[u]);
        float ss = 0.f;
        for (int u = 0; u < NV; ++u) ss += expf(sl[u] - mx);
        outp[(size_t)b * NV + t] = expf(sl[t] - mx) / ss;
    }
}

extern "C" void kernel_launch(void* const* d_in, const int* in_sizes, int n_in,
                              void* d_out, int out_size, void* d_ws, size_t ws_size,
                              hipStream_t stream) {
    const int*   x    = (const int*)d_in[0];
    const float* eemb = (const float*)d_in[1];
    const float* ecw  = (const float*)d_in[2];
    const float* ecb  = (const float*)d_in[3];
    const float* elw  = (const float*)d_in[4];
    const float* elb  = (const float*)d_in[5];
    // d_in[6] rand_proj: provably unused (fog_of_war returns identity permutation)
    const float* mcw  = (const float*)d_in[7];
    const float* mcb  = (const float*)d_in[8];
    const float* mlw  = (const float*)d_in[9];
    const float* mlb  = (const float*)d_in[10];
    const float* femb = (const float*)d_in[11];
    const float* fcw  = (const float*)d_in[12];
    const float* fcb  = (const float*)d_in[13];
    const float* flw1 = (const float*)d_in[14];
    const float* flb1 = (const float*)d_in[15];
    const float* fl2  = (const float*)d_in[16];
    const float* fb2  = (const float*)d_in[17];
    float* outp = (float*)d_out;

    char* w = (char*)d_ws;
    size_t off = 0;
    auto alloc = [&](size_t bytes) {
        void* p = w + off;
        off = (off + bytes + 255) & ~(size_t)255;
        return p;
    };
    float* cwT    = (float*)alloc(2ull * 3 * EMBD * OC * 4);    // 3.1 MB
    float* C      = (float*)alloc(2ull * NP * 3 * OC * 4);      // 1.2 MB
    float* Wc     = (float*)alloc(3ull * 128 * 64 * 4);
    float* Lint   = (float*)alloc(64ull * MJ * 4);
    int*   tokens = (int*)alloc((size_t)BB * LL * 4);
    float* partial= (float*)alloc((size_t)BB * H2 * JD * 4);    // 16.8 MB, [b][h][j]

    const float* C_e = C;
    const float* C_f = C + (size_t)NP * 3 * OC;

    // ---- prep (cwt | manipw | lint) ----
    k_prep<<<PB_CWT + PB_MANIPW + PB_LINT, 256, 0, stream>>>(
        ecw, fcw, mcw, mlw, cwT, Wc, Lint);
    // ---- pair contributions (i-split x2, q-batch 4, inline pair-max, cb folded) ----
    k_contrib<<<2 * 3 * 49, 512, 0, stream>>>(eemb, femb, cwT, ecb, fcb, C);

    // ---- enemy branch (bf16x3 MFMA — token path needs near-fp32) ----
    k_gemm<1, 32><<<dim3(H2, 4), 512, 0, stream>>>(x, C_e, elw, partial);
    k_fuseE<<<BB, 256, 0, stream>>>(partial, elb, Wc, mcb, mlw, Lint, mlb, tokens);

    // ---- friend branch (plain bf16 MFMA, single-barrier full-K) ----
    k_gemmF1<<<dim3(H2, 2), 512, 0, stream>>>(tokens, C_f, flw1, partial);
    k_fuseF<<<BB, 256, 0, stream>>>(partial, flb1, fl2, fb2, outp);
}

// Round 13
// 74.318 us; speedup vs baseline: 1.1977x; 1.1977x over previous
//
#include <hip/hip_runtime.h>
#include <hip/hip_bf16.h>
#include <math.h>

#define BB    256   // batch
#define LL    256   // seq len
#define NV    14    // vocab
#define EMBD  512
#define H2    128   // L//2
#define OC    256   // branch conv out channels
#define NP    196   // 14*14 ordered token pairs
#define JD    128   // branch linear out
#define MO    64    // manip conv out channels
#define MJ    256   // manip linear out

#define CB_MAIN   294                   // contrib main blocks (2*3*49)
#define CB_MANIPW 48                    // 3*128*64 / 512
#define CB_LINT   32                    // 64 o's, 2 per block

using s16x8 = __attribute__((ext_vector_type(8))) short;
using f32x4 = __attribute__((ext_vector_type(4))) float;

static __device__ __forceinline__ unsigned short f2bf_rne(float f) {
    unsigned int u = __float_as_uint(f);
    unsigned int r = (u + 0x7FFFu + ((u >> 16) & 1u)) >> 16;
    return (unsigned short)r;
}
static __device__ __forceinline__ float bf2f(unsigned short h) {
    return __uint_as_float(((unsigned int)h) << 16);
}

// ---------- prep: cwt LDS transpose only ----------
__global__ void k_prep(const float* __restrict__ cw_e, const float* __restrict__ cw_f,
                       float* __restrict__ cwT) {
    __shared__ float T[48][66];
    int bid = blockIdx.x;              // 0..255
    int t = threadIdx.x;
    int ic = bid & 31;                 // i-chunk (16 i's)
    int oc = (bid >> 5) & 3;           // o-chunk (64 o's)
    int br = bid >> 7;                 // branch
    int i0 = ic * 16, o0 = oc * 64;
    const float* cw = br ? cw_f : cw_e;
    int ol = t >> 2, part = t & 3;
    const float* src = cw + ((size_t)(o0 + ol) * EMBD + i0) * 9 + part * 36;
    #pragma unroll
    for (int ii = 0; ii < 4; ++ii)
        #pragma unroll
        for (int kh = 0; kh < 3; ++kh)
            T[kh * 16 + part * 4 + ii][ol] = src[ii * 9 + kh * 3 + 1];
    __syncthreads();
    int lane = t & 63, r0 = t >> 6;
    for (int rr = r0; rr < 48; rr += 4) {
        int kh = rr >> 4, il = rr & 15;
        cwT[(((size_t)(br * 3 + kh)) * EMBD + i0 + il) * OC + o0 + lane] = T[rr][lane];
    }
}

// ---------- contrib: pair contributions | manipw | lint ----------
__global__ __launch_bounds__(512) void k_contrib(
        const float* __restrict__ emb_e, const float* __restrict__ emb_f,
        const float* __restrict__ cwT,
        const float* __restrict__ cb_e, const float* __restrict__ cb_f,
        const float* __restrict__ mcw, const float* __restrict__ mlw,
        float* __restrict__ C, float* __restrict__ Wc, float* __restrict__ Lint) {
    int bid = blockIdx.x;
    int t = threadIdx.x;
    if (bid < CB_MAIN) {                // pair contributions, i-split x2, q-batch 4
        int qg = bid % 49;
        int kh = (bid / 49) % 3;
        int br = bid / 147;
        int o = t & 255, ih = t >> 8;
        const float* emb = br ? emb_f : emb_e;

        __shared__ float Pl[4][512];
        __shared__ float Rd[4][2][256];
        for (int idx = t; idx < 4 * 512; idx += 512) {
            int row = idx >> 9, col = idx & 511;
            int q = qg * 4 + row;
            int t1 = q / NV, t2 = q % NV;
            Pl[row][col] = fmaxf(emb[t1 * EMBD + col], emb[t2 * EMBD + col]);
        }
        __syncthreads();

        const float* w = cwT + ((size_t)(br * 3 + kh) * EMBD + ih * 256) * OC + o;
        float acc[4] = {0.f, 0.f, 0.f, 0.f};
        #pragma unroll 8
        for (int i = 0; i < 256; i++) {
            float wv = w[(size_t)i * OC];
            #pragma unroll
            for (int qq = 0; qq < 4; qq++) acc[qq] = fmaf(wv, Pl[qq][ih * 256 + i], acc[qq]);
        }
        #pragma unroll
        for (int qq = 0; qq < 4; qq++) Rd[qq][ih][o] = acc[qq];
        __syncthreads();
        if (t < 256) {
            float cbv = (kh == 1) ? (br ? cb_f[o] : cb_e[o]) : 0.f;
            #pragma unroll
            for (int qq = 0; qq < 4; qq++)
                C[(((size_t)br * NP + qg * 4 + qq) * 3 + kh) * OC + o] =
                    Rd[qq][0][o] + Rd[qq][1][o] + cbv;
        }
    } else if (bid < CB_MAIN + CB_MANIPW) {   // manipw
        int idx = (bid - CB_MAIN) * 512 + t;
        int o = idx & 63;
        int i = (idx >> 6) & 127;
        int cls = idx >> 13;
        const float* base = mcw + ((size_t)(o * 128 + i) * 3) * 3 + 1;
        float v = 0.f;
        if (cls != 2) { v += base[3]; v += base[6]; }
        else          { v += base[0]; v += base[3]; }
        if (cls == 1)   v += base[0];
        Wc[idx] = v;
    } else {                                   // lint: 2 o's per block
        int lb = bid - (CB_MAIN + CB_MANIPW);  // 0..31
        int o = lb * 2 + (t >> 8);
        int j = t & 255;
        float s = 0.f;
        for (int h = 1; h <= 126; h++)
            s += mlw[((size_t)(o * H2 + h)) * MJ + j];
        Lint[o * 256 + j] = s;
    }
}

// ---------- MFMA GEMM: partial[b][h][j] = sum_o Y[b,h,o]*lw[(o*H2+h)*JD+j] ----------
// M-tile 64, grid (H2, 4) = 512 blocks, 8 waves 2m x 4n. SK = K per LDS stage.
// B-staging: thread owns 4 consecutive j x (SK/16) k's; float4 loads on
// contiguous rows; packed LDS writes. X3=1: bf16 hi/lo 3-product split.
template <int X3, int SK>
__global__ __launch_bounds__(512) void k_gemm(
        const int* __restrict__ tok, const float* __restrict__ C,
        const float* __restrict__ lw, float* __restrict__ partial) {
    __shared__ unsigned short Ah[2][64][SK + 4];
    __shared__ unsigned short Al[X3 ? 2 : 1][X3 ? 64 : 1][X3 ? SK + 4 : 1];
    __shared__ unsigned short Bh[2][128][SK + 4];
    __shared__ unsigned short Bl[X3 ? 2 : 1][X3 ? 128 : 1][X3 ? SK + 4 : 1];

    const int h  = blockIdx.x;
    const int B0 = blockIdx.y * 64;
    const int t  = threadIdx.x;
    constexpr int NST = 256 / SK;
    constexpr int KQ  = SK / 8;
    constexpr int KPT = SK / 16;

    const int am = t >> 3;
    const int kq = (t & 7) * KQ;
    const int* tb = tok + (size_t)(B0 + am) * LL;
    const int q1 = tb[2 * h] * NV + tb[2 * h + 1];
    const float* r1 = C + ((size_t)q1 * 3 + 1) * OC + kq;
    const float* r0 = nullptr;
    const float* r2 = nullptr;
    if (h > 0)      { int q0 = tb[2 * h - 2] * NV + tb[2 * h - 1]; r0 = C + ((size_t)q0 * 3 + 0) * OC + kq; }
    if (h < H2 - 1) { int q2 = tb[2 * h + 2] * NV + tb[2 * h + 3]; r2 = C + ((size_t)q2 * 3 + 2) * OC + kq; }

    const int j0b = (t & 31) * 4;
    const int k0  = (t >> 5) * KPT;
    const float* wsrc = lw + (((size_t)k0 * H2) + h) * JD + j0b;

    float4 ya[SK / 32], yb[SK / 32], yc[SK / 32], wv4[KPT];

    auto load = [&](int s) {
        #pragma unroll
        for (int p = 0; p < SK / 32; ++p) {
            ya[p] = *(const float4*)(r1 + s * SK + 4 * p);
            if (r0) yb[p] = *(const float4*)(r0 + s * SK + 4 * p);
            else    yb[p] = make_float4(0, 0, 0, 0);
            if (r2) yc[p] = *(const float4*)(r2 + s * SK + 4 * p);
            else    yc[p] = make_float4(0, 0, 0, 0);
        }
        #pragma unroll
        for (int kk = 0; kk < KPT; ++kk)
            wv4[kk] = *(const float4*)(wsrc + ((size_t)(s * SK) + kk) * (H2 * JD));
    };

    auto store = [&](int buf) {
        #pragma unroll
        for (int p = 0; p < SK / 32; ++p) {
            float y[4];
            y[0] = ya[p].x + yb[p].x + yc[p].x; y[1] = ya[p].y + yb[p].y + yc[p].y;
            y[2] = ya[p].z + yb[p].z + yc[p].z; y[3] = ya[p].w + yb[p].w + yc[p].w;
            unsigned short hi[4];
            #pragma unroll
            for (int e = 0; e < 4; ++e) hi[e] = f2bf_rne(y[e]);
            uint2 u;
            u.x = (unsigned)hi[0] | ((unsigned)hi[1] << 16);
            u.y = (unsigned)hi[2] | ((unsigned)hi[3] << 16);
            *(uint2*)&Ah[buf][am][kq + 4 * p] = u;
            if (X3) {
                unsigned short lo[4];
                #pragma unroll
                for (int e = 0; e < 4; ++e) lo[e] = f2bf_rne(y[e] - bf2f(hi[e]));
                uint2 v;
                v.x = (unsigned)lo[0] | ((unsigned)lo[1] << 16);
                v.y = (unsigned)lo[2] | ((unsigned)lo[3] << 16);
                *(uint2*)&Al[buf][am][kq + 4 * p] = v;
            }
        }
        #pragma unroll
        for (int jj = 0; jj < 4; ++jj) {
            unsigned short hb[KPT], lb[KPT];
            #pragma unroll
            for (int kk = 0; kk < KPT; ++kk) {
                float wf = ((const float*)&wv4[kk])[jj];
                hb[kk] = f2bf_rne(wf);
                if (X3) lb[kk] = f2bf_rne(wf - bf2f(hb[kk]));
            }
            if constexpr (KPT == 2) {
                *(unsigned*)&Bh[buf][j0b + jj][k0] = (unsigned)hb[0] | ((unsigned)hb[1] << 16);
                if (X3) *(unsigned*)&Bl[buf][j0b + jj][k0] = (unsigned)lb[0] | ((unsigned)lb[1] << 16);
            } else {
                uint2 u;
                u.x = (unsigned)hb[0] | ((unsigned)hb[1] << 16);
                u.y = (unsigned)hb[2] | ((unsigned)hb[3] << 16);
                *(uint2*)&Bh[buf][j0b + jj][k0] = u;
                if (X3) {
                    uint2 v;
                    v.x = (unsigned)lb[0] | ((unsigned)lb[1] << 16);
                    v.y = (unsigned)lb[2] | ((unsigned)lb[3] << 16);
                    *(uint2*)&Bl[buf][j0b + jj][k0] = v;
                }
            }
        }
    };

    const int lane = t & 63, wid = t >> 6;
    const int Wm = (wid >> 2) * 32;
    const int Wn = (wid & 3) * 32;
    const int fr = lane & 15;
    const int g8 = (lane >> 4) * 8;

    f32x4 acc[2][2] = {};

    auto rd8 = [&](const unsigned short* p) -> s16x8 {
        union { s16x8 v; uint2 u[2]; } tmp;
        tmp.u[0] = *(const uint2*)(p);
        tmp.u[1] = *(const uint2*)(p + 4);
        return tmp.v;
    };

    auto compute = [&](int buf) {
        #pragma unroll
        for (int kk0 = 0; kk0 < SK; kk0 += 32) {
            s16x8 a_h[2], b_h[2];
            #pragma unroll
            for (int mf = 0; mf < 2; ++mf) a_h[mf] = rd8(&Ah[buf][Wm + mf * 16 + fr][kk0 + g8]);
            #pragma unroll
            for (int nf = 0; nf < 2; ++nf) b_h[nf] = rd8(&Bh[buf][Wn + nf * 16 + fr][kk0 + g8]);
            #pragma unroll
            for (int mf = 0; mf < 2; ++mf)
                #pragma unroll
                for (int nf = 0; nf < 2; ++nf)
                    acc[mf][nf] = __builtin_amdgcn_mfma_f32_16x16x32_bf16(a_h[mf], b_h[nf], acc[mf][nf], 0, 0, 0);
            if (X3) {
                s16x8 a_l[2], b_l[2];
                #pragma unroll
                for (int mf = 0; mf < 2; ++mf) a_l[mf] = rd8(&Al[buf][Wm + mf * 16 + fr][kk0 + g8]);
                #pragma unroll
                for (int nf = 0; nf < 2; ++nf) b_l[nf] = rd8(&Bl[buf][Wn + nf * 16 + fr][kk0 + g8]);
                #pragma unroll
                for (int mf = 0; mf < 2; ++mf)
                    #pragma unroll
                    for (int nf = 0; nf < 2; ++nf) {
                        acc[mf][nf] = __builtin_amdgcn_mfma_f32_16x16x32_bf16(a_h[mf], b_l[nf], acc[mf][nf], 0, 0, 0);
                        acc[mf][nf] = __builtin_amdgcn_mfma_f32_16x16x32_bf16(a_l[mf], b_h[nf], acc[mf][nf], 0, 0, 0);
                    }
            }
        }
    };

    load(0);
    store(0);
    __syncthreads();
    for (int s = 0; s < NST; ++s) {
        if (s < NST - 1) load(s + 1);
        compute(s & 1);
        if (s < NST - 1) store((s + 1) & 1);
        __syncthreads();
    }

    float* pb = partial + (((size_t)(B0 + Wm)) * H2 + h) * JD + Wn;
    #pragma unroll
    for (int mf = 0; mf < 2; ++mf)
        #pragma unroll
        for (int nf = 0; nf < 2; ++nf)
            #pragma unroll
            for (int r = 0; r < 4; ++r) {
                int row = mf * 16 + (lane >> 4) * 4 + r;
                int col = nf * 16 + fr;
                pb[(size_t)row * H2 * JD + col] = acc[mf][nf][r];
            }
}

// ---------- fuse E (512 thr): reduce + softmax + manip conv + linear + tokens ----------
__global__ __launch_bounds__(512) void k_fuseE(
        const float* __restrict__ partial, const float* __restrict__ elb,
        const float* __restrict__ Wc, const float* __restrict__ mcb,
        const float* __restrict__ mlw, const float* __restrict__ Lint,
        const float* __restrict__ mlb, int* __restrict__ tokens) {
    int b = blockIdx.x, t = threadIdx.x;
    __shared__ float S[4][128];
    __shared__ float eo[128];
    __shared__ float m3[3][64];
    __shared__ float red[128];
    __shared__ float mt[2][256];

    int j = t & 127, hh = t >> 7;       // hh 0..3
    float s = 0.f;
    const float* pbase = partial + (size_t)b * H2 * JD + j;
    for (int h = hh * 32; h < hh * 32 + 32; ++h)
        s += pbase[(size_t)h * JD];
    S[hh][j] = s;
    __syncthreads();
    if (t < 128) {
        float v = (S[0][t] + S[1][t]) + (S[2][t] + S[3][t]) + elb[t];
        S[0][t] = v;
        red[t] = v;
    }
    __syncthreads();
    for (int st = 64; st > 0; st >>= 1) {
        if (t < st) red[t] = fmaxf(red[t], red[t + st]);
        __syncthreads();
    }
    float mx = red[0];
    __syncthreads();
    if (t < 128) {
        float e = expf(S[0][t] - mx);
        eo[t] = e;
        red[t] = e;
    }
    __syncthreads();
    for (int st = 64; st > 0; st >>= 1) {
        if (t < st) red[t] += red[t + st];
        __syncthreads();
    }
    float inv = 1.f / red[0];
    __syncthreads();
    if (t < 128) eo[t] *= inv;
    __syncthreads();
    // manip conv values
    if (t < 192) {
        int cls = t >> 6, o = t & 63;
        float a = mcb[o];
        const float* wp = Wc + (size_t)cls * 128 * 64 + o;
        for (int i = 0; i < 128; ++i) a = fmaf(eo[i], wp[(size_t)i * 64], a);
        m3[cls][o] = fmaxf(a, 0.f);
    }
    __syncthreads();
    // manip linear + tokens, o-loop split 2-way across thread halves
    {
        int ihh = t >> 8, jj = t & 255;
        float a = ihh ? 0.f : mlb[jj];
        for (int o = ihh * 32; o < ihh * 32 + 32; ++o) {
            a = fmaf(m3[0][o], mlw[((size_t)(o * H2 + 0)) * MJ + jj], a);
            a = fmaf(m3[1][o], Lint[(size_t)o * MJ + jj], a);
            a = fmaf(m3[2][o], mlw[((size_t)(o * H2 + 127)) * MJ + jj], a);
        }
        mt[ihh][jj] = a;
    }
    __syncthreads();
    if (t < 256) {
        float a = mt[0][t] + mt[1][t];
        tokens[(size_t)b * LL + t] = ((int)floorf(fabsf(a) * 100.f)) % NV;
    }
}

// ---------- fuse F (512 thr): reduce + head linear + softmax(14) ----------
__global__ __launch_bounds__(512) void k_fuseF(
        const float* __restrict__ partial, const float* __restrict__ flb1,
        const float* __restrict__ fl2, const float* __restrict__ fb2,
        float* __restrict__ outp) {
    int b = blockIdx.x, t = threadIdx.x;
    __shared__ float S[4][128];
    __shared__ float f1[128];
    __shared__ float sl[NV];
    int j = t & 127, hh = t >> 7;
    float s = 0.f;
    const float* pbase = partial + (size_t)b * H2 * JD + j;
    for (int h = hh * 32; h < hh * 32 + 32; ++h)
        s += pbase[(size_t)h * JD];
    S[hh][j] = s;
    __syncthreads();
    if (t < 128) f1[t] = (S[0][t] + S[1][t]) + (S[2][t] + S[3][t]) + flb1[t];
    __syncthreads();
    if (t < NV) {
        float a = fb2[t];
        for (int jj = 0; jj < 128; ++jj) a = fmaf(f1[jj], fl2[(size_t)jj * NV + t], a);
        sl[t] = a;
    }
    __syncthreads();
    if (t < NV) {
        float mx = -1e30f;
        for (int u = 0; u < NV; ++u) mx = fmaxf(mx, sl[u]);
        float ss = 0.f;
        for (int u = 0; u < NV; ++u) ss += expf(sl[u] - mx);
        outp[(size_t)b * NV + t] = expf(sl[t] - mx) / ss;
    }
}

extern "C" void kernel_launch(void* const* d_in, const int* in_sizes, int n_in,
                              void* d_out, int out_size, void* d_ws, size_t ws_size,
                              hipStream_t stream) {
    const int*   x    = (const int*)d_in[0];
    const float* eemb = (const float*)d_in[1];
    const float* ecw  = (const float*)d_in[2];
    const float* ecb  = (const float*)d_in[3];
    const float* elw  = (const float*)d_in[4];
    const float* elb  = (const float*)d_in[5];
    // d_in[6] rand_proj: provably unused (fog_of_war returns identity permutation)
    const float* mcw  = (const float*)d_in[7];
    const float* mcb  = (const float*)d_in[8];
    const float* mlw  = (const float*)d_in[9];
    const float* mlb  = (const float*)d_in[10];
    const float* femb = (const float*)d_in[11];
    const float* fcw  = (const float*)d_in[12];
    const float* fcb  = (const float*)d_in[13];
    const float* flw1 = (const float*)d_in[14];
    const float* flb1 = (const float*)d_in[15];
    const float* fl2  = (const float*)d_in[16];
    const float* fb2  = (const float*)d_in[17];
    float* outp = (float*)d_out;

    char* w = (char*)d_ws;
    size_t off = 0;
    auto alloc = [&](size_t bytes) {
        void* p = w + off;
        off = (off + bytes + 255) & ~(size_t)255;
        return p;
    };
    float* cwT    = (float*)alloc(2ull * 3 * EMBD * OC * 4);    // 3.1 MB
    float* C      = (float*)alloc(2ull * NP * 3 * OC * 4);      // 1.2 MB
    float* Wc     = (float*)alloc(3ull * 128 * 64 * 4);
    float* Lint   = (float*)alloc(64ull * MJ * 4);
    int*   tokens = (int*)alloc((size_t)BB * LL * 4);
    float* partial= (float*)alloc((size_t)BB * H2 * JD * 4);    // 16.8 MB, [b][h][j]

    const float* C_e = C;
    const float* C_f = C + (size_t)NP * 3 * OC;

    // ---- prep (cwt transpose only) ----
    k_prep<<<256, 256, 0, stream>>>(ecw, fcw, cwT);
    // ---- contrib (pair contributions | manipw | lint) ----
    k_contrib<<<CB_MAIN + CB_MANIPW + CB_LINT, 512, 0, stream>>>(
        eemb, femb, cwT, ecb, fcb, mcw, mlw, C, Wc, Lint);

    // ---- enemy branch (bf16x3 MFMA — token path needs near-fp32) ----
    k_gemm<1, 32><<<dim3(H2, 4), 512, 0, stream>>>(x, C_e, elw, partial);
    k_fuseE<<<BB, 512, 0, stream>>>(partial, elb, Wc, mcb, mlw, Lint, mlb, tokens);

    // ---- friend branch (plain bf16 MFMA, K-stage 64) ----
    k_gemm<0, 64><<<dim3(H2, 4), 512, 0, stream>>>(tokens, C_f, flw1, partial);
    k_fuseF<<<BB, 512, 0, stream>>>(partial, flb1, fl2, fb2, outp);
}